// Round 9
// baseline (193.190 us; speedup 1.0000x reference)
//
#include <hip/hip_runtime.h>
#include <stdint.h>

typedef unsigned short u16;
typedef __bf16 bf16;
typedef __bf16 bf16x8 __attribute__((ext_vector_type(8)));
typedef float f32x4 __attribute__((ext_vector_type(4)));

#define NSEQ 2048
#define NDH 64
#define NH 8
#define QKS 2097152ull  // elements per q/k/v/t plane

__device__ __forceinline__ float b2f(u16 u) {
  union { float f; uint32_t i; } x; x.i = ((uint32_t)u) << 16; return x.f;
}
__device__ __forceinline__ u16 f2b(float f) {
  union { float f; uint32_t i; } x; x.f = f;
  const uint32_t r = x.i + 0x7FFFu + ((x.i >> 16) & 1u);
  return (u16)(r >> 16);
}

// ---------------------------------------------------------------------------
// K0: one-shot fp32 -> bf16 conversion of x, w_qkv, w_out.
// ---------------------------------------------------------------------------
__global__ __launch_bounds__(256) void k_cvt(
    const float* __restrict__ x, const float* __restrict__ wqkv,
    const float* __restrict__ wout, u16* __restrict__ xbf,
    u16* __restrict__ wqkvbf, u16* __restrict__ woutbf) {
  const int i = blockIdx.x * 256 + threadIdx.x;
  const float* src; u16* dst; int off;
  if (i < 524288)      { src = x;    dst = xbf;    off = i; }
  else if (i < 786432) { src = wqkv; dst = wqkvbf; off = i - 524288; }
  else                 { src = wout; dst = woutbf; off = i - 786432; }
  const float4 v = *(const float4*)(src + (size_t)off * 4);
  u16 t[4] = {f2b(v.x), f2b(v.y), f2b(v.z), f2b(v.w)};
  *(uint2*)(dst + (size_t)off * 4) = *(const uint2*)t;
}

// ---------------------------------------------------------------------------
// K1: qkvt = Xbf[4096,512] @ Wbf[2048,512]^T (MFMA 16x16x32 bf16).
// q plane pre-scaled by dh^-0.5 * log2(e). V plane stored transposed
// [b,h,dim,tok]. LDS-transpose epilogue -> coalesced uint4 stores.
// ---------------------------------------------------------------------------
__global__ __launch_bounds__(256) void k_gemm_qkvt(
    const u16* __restrict__ X, const u16* __restrict__ W, u16* __restrict__ qkvt) {
  __shared__ __align__(16) bf16 smem[18432];  // stage 10240 | epi 4x(64x72)
  bf16* As = smem;          // [128][40]
  bf16* Bs = smem + 5120;   // [128][40]
  const int tid = threadIdx.x;
  const int n0 = blockIdx.x * 128;
  const int m0 = blockIdx.y * 128;
  const int w = tid >> 6, lane = tid & 63;
  const int wy = w >> 1, wx = w & 1;
  const int quad = lane >> 4, l15 = lane & 15;
  const int srow = tid >> 1, shalf = (tid & 1) * 16;
  const u16* ax = X + (size_t)(m0 + srow) * 512 + shalf;
  const u16* bx = W + (size_t)(n0 + srow) * 512 + shalf;
  f32x4 acc[4][4];
#pragma unroll
  for (int mt = 0; mt < 4; ++mt)
#pragma unroll
    for (int nt = 0; nt < 4; ++nt) acc[mt][nt] = (f32x4){0.f, 0.f, 0.f, 0.f};
  uint4 a0 = *(const uint4*)ax, a1 = *(const uint4*)(ax + 8);
  uint4 b0 = *(const uint4*)bx, b1 = *(const uint4*)(bx + 8);
  for (int kc = 0; kc < 512; kc += 32) {
    __syncthreads();
    *(uint4*)&As[srow * 40 + shalf]     = a0;
    *(uint4*)&As[srow * 40 + shalf + 8] = a1;
    *(uint4*)&Bs[srow * 40 + shalf]     = b0;
    *(uint4*)&Bs[srow * 40 + shalf + 8] = b1;
    __syncthreads();
    if (kc + 32 < 512) {
      a0 = *(const uint4*)(ax + kc + 32);
      a1 = *(const uint4*)(ax + kc + 40);
      b0 = *(const uint4*)(bx + kc + 32);
      b1 = *(const uint4*)(bx + kc + 40);
    }
    bf16x8 af[4], bfr[4];
#pragma unroll
    for (int mt = 0; mt < 4; ++mt)
      af[mt] = *(const bf16x8*)&As[(wy * 64 + mt * 16 + l15) * 40 + quad * 8];
#pragma unroll
    for (int nt = 0; nt < 4; ++nt)
      bfr[nt] = *(const bf16x8*)&Bs[(wx * 64 + nt * 16 + l15) * 40 + quad * 8];
#pragma unroll
    for (int mt = 0; mt < 4; ++mt)
#pragma unroll
      for (int nt = 0; nt < 4; ++nt)
        acc[mt][nt] = __builtin_amdgcn_mfma_f32_16x16x32_bf16(af[mt], bfr[nt], acc[mt][nt], 0, 0, 0);
  }
  __syncthreads();   // staging reads done; reuse smem for epilogue
  const int cbase = n0 + wx * 64;
  const int which = cbase >> 9;       // 0=q 1=k 2=v 3=t
  const int h     = (cbase >> 6) & 7;
  // q scale: dh^-0.5 * log2(e) so attention exp is raw exp2
  const float scale = (which == 0) ? 0.18033688011112043f : 1.0f;
  bf16* Cw = smem + w * 4608;         // per-wave [64][72]
  if (which == 2) {
#pragma unroll
    for (int nt = 0; nt < 4; ++nt)
#pragma unroll
      for (int mt = 0; mt < 4; ++mt)
#pragma unroll
        for (int r = 0; r < 4; ++r)
          Cw[(nt * 16 + l15) * 72 + mt * 16 + quad * 4 + r] = (bf16)acc[mt][nt][r];
  } else {
#pragma unroll
    for (int mt = 0; mt < 4; ++mt)
#pragma unroll
      for (int nt = 0; nt < 4; ++nt)
#pragma unroll
        for (int r = 0; r < 4; ++r)
          Cw[(mt * 16 + quad * 4 + r) * 72 + nt * 16 + l15] = (bf16)(acc[mt][nt][r] * scale);
  }
  const int mb = m0 + wy * 64;
  const int bb = mb >> 11;
  const int nn0 = mb & (NSEQ - 1);
  if (which == 2) {
    u16* vt = qkvt + 2ull * QKS + (size_t)(bb * NH + h) * NDH * NSEQ;
#pragma unroll
    for (int p = 0; p < 8; ++p) {
      const int d = p * 8 + (lane >> 3);
      const int t8 = (lane & 7) * 8;
      const uint4 v = *(const uint4*)&Cw[d * 72 + t8];
      *(uint4*)(vt + (size_t)d * NSEQ + nn0 + t8) = v;
    }
  } else {
    u16* dst = qkvt + (size_t)which * QKS + ((size_t)(bb * NH + h) * NSEQ + nn0) * NDH;
#pragma unroll
    for (int p = 0; p < 8; ++p) {
      const int tok = p * 8 + (lane >> 3);
      const int c8 = (lane & 7) * 8;
      const uint4 v = *(const uint4*)&Cw[tok * 72 + c8];
      *(uint4*)(dst + (size_t)tok * NDH + c8) = v;
    }
  }
}

// ---------------------------------------------------------------------------
// K2: MFMA flash attention. 64-query tile, 2 waves x 32 q/wave (each K/V
// frag read feeds 2 MFMAs), 128 thr/block. LDS 36.5 KB -> 4 blocks/CU
// (8 waves/CU: TLP to cover barrier drains). No-max softmax via exp2,
// l via ones-column MFMA. Pw stride 76 (quad-stride 152%32=24: <=2-way).
// Grid (bh, qtile): linear dispatch keeps one bh's K/V on one XCD's L2.
// ---------------------------------------------------------------------------
__global__ __launch_bounds__(128) void k_attn(
    const u16* __restrict__ qkvt, u16* __restrict__ out12) {
  __shared__ __align__(16) bf16 Qs[64][72];
  __shared__ __align__(16) bf16 Ks[64][72];
  __shared__ __align__(16) bf16 Vt[64][72];   // [dim][key]
  __shared__ __align__(16) bf16 Pw[64][76];   // per-wave 32-row regions
  const int tid = threadIdx.x;
  const int bh  = blockIdx.x;
  const int q0  = blockIdx.y * 64;
  const size_t base  = (size_t)bh * (NSEQ * NDH);
  const size_t vbase = 2ull * QKS + (size_t)bh * (NDH * NSEQ);
  const int wq = tid >> 6, lane = tid & 63;
  const int quad = lane >> 4, l15 = lane & 15;
  const int srow = tid >> 1, shalf = (tid & 1) * 32;
  { // stage 64 Q rows: each thread 32 elems (4x uint4)
    const u16* qp = qkvt + base + (size_t)(q0 + srow) * NDH + shalf;
    *(uint4*)&Qs[srow][shalf]      = *(const uint4*)qp;
    *(uint4*)&Qs[srow][shalf + 8]  = *(const uint4*)(qp + 8);
    *(uint4*)&Qs[srow][shalf + 16] = *(const uint4*)(qp + 16);
    *(uint4*)&Qs[srow][shalf + 24] = *(const uint4*)(qp + 24);
  }
  __syncthreads();
  bf16x8 qa[2][2];
#pragma unroll
  for (int i = 0; i < 2; ++i)
#pragma unroll
    for (int c = 0; c < 2; ++c)
      qa[i][c] = *(const bf16x8*)&Qs[wq * 32 + i * 16 + l15][c * 32 + quad * 8];
  bf16x8 vones;
#pragma unroll
  for (int j = 0; j < 8; ++j) vones[j] = (l15 == 0) ? (bf16)1.f : (bf16)0.f;
  f32x4 lacc[2] = {{0.f,0.f,0.f,0.f},{0.f,0.f,0.f,0.f}};
  f32x4 o[2][4];
#pragma unroll
  for (int i = 0; i < 2; ++i)
#pragma unroll
    for (int nt = 0; nt < 4; ++nt) o[i][nt] = (f32x4){0.f,0.f,0.f,0.f};
  const u16* kp = qkvt + QKS + base + (size_t)srow * NDH + shalf;
  const u16* vp = qkvt + vbase + (size_t)srow * NSEQ + shalf;
  uint4 kr[4], vr[4];
#pragma unroll
  for (int p = 0; p < 4; ++p) {
    kr[p] = *(const uint4*)(kp + p * 8);
    vr[p] = *(const uint4*)(vp + p * 8);
  }
  for (int kt = 0; kt < 32; ++kt) {
    __syncthreads();
#pragma unroll
    for (int p = 0; p < 4; ++p) {
      *(uint4*)&Ks[srow][shalf + p * 8] = kr[p];
      *(uint4*)&Vt[srow][shalf + p * 8] = vr[p];
    }
    __syncthreads();
    if (kt < 31) {   // prefetch next tile during compute
      const u16* kn = kp + (size_t)(kt + 1) * 64 * NDH;
      const u16* vn = vp + (kt + 1) * 64;
#pragma unroll
      for (int p = 0; p < 4; ++p) {
        kr[p] = *(const uint4*)(kn + p * 8);
        vr[p] = *(const uint4*)(vn + p * 8);
      }
    }
    f32x4 s[2][4];
#pragma unroll
    for (int i = 0; i < 2; ++i)
#pragma unroll
      for (int t = 0; t < 4; ++t) s[i][t] = (f32x4){0.f,0.f,0.f,0.f};
#pragma unroll
    for (int t = 0; t < 4; ++t) {
      const bf16x8 kb0 = *(const bf16x8*)&Ks[t * 16 + l15][quad * 8];
      const bf16x8 kb1 = *(const bf16x8*)&Ks[t * 16 + l15][32 + quad * 8];
#pragma unroll
      for (int i = 0; i < 2; ++i) {
        s[i][t] = __builtin_amdgcn_mfma_f32_16x16x32_bf16(qa[i][0], kb0, s[i][t], 0, 0, 0);
        s[i][t] = __builtin_amdgcn_mfma_f32_16x16x32_bf16(qa[i][1], kb1, s[i][t], 0, 0, 0);
      }
    }
    // p = exp2(s); P -> per-wave LDS region (stride 76: conflict-free)
#pragma unroll
    for (int i = 0; i < 2; ++i)
#pragma unroll
      for (int r = 0; r < 4; ++r) {
        const int prow = wq * 32 + i * 16 + quad * 4 + r;
        Pw[prow][l15]      = (bf16)__builtin_amdgcn_exp2f(s[i][0][r]);
        Pw[prow][16 + l15] = (bf16)__builtin_amdgcn_exp2f(s[i][1][r]);
        Pw[prow][32 + l15] = (bf16)__builtin_amdgcn_exp2f(s[i][2][r]);
        Pw[prow][48 + l15] = (bf16)__builtin_amdgcn_exp2f(s[i][3][r]);
      }
    // wave-local P region: no barrier needed before re-read
#pragma unroll
    for (int c = 0; c < 2; ++c) {
      bf16x8 pa[2];
#pragma unroll
      for (int i = 0; i < 2; ++i) {
        pa[i] = *(const bf16x8*)&Pw[wq * 32 + i * 16 + l15][c * 32 + quad * 8];
        lacc[i] = __builtin_amdgcn_mfma_f32_16x16x32_bf16(pa[i], vones, lacc[i], 0, 0, 0);
      }
#pragma unroll
      for (int nt = 0; nt < 4; ++nt) {
        const bf16x8 vb = *(const bf16x8*)&Vt[nt * 16 + l15][c * 32 + quad * 8];
#pragma unroll
        for (int i = 0; i < 2; ++i)
          o[i][nt] = __builtin_amdgcn_mfma_f32_16x16x32_bf16(pa[i], vb, o[i][nt], 0, 0, 0);
      }
    }
  }
  const int bb = bh >> 3, h = bh & 7;
#pragma unroll
  for (int i = 0; i < 2; ++i)
#pragma unroll
    for (int r = 0; r < 4; ++r) {
      const float lsum = __shfl(lacc[i][r], lane & 48);  // col 0 of quad's row
      const float inv = 1.f / lsum;
      const int nn = q0 + wq * 32 + i * 16 + quad * 4 + r;
      u16* dst = out12 + (size_t)(bb * NSEQ + nn) * 1024 + h * 128;
#pragma unroll
      for (int nt = 0; nt < 4; ++nt)
        dst[nt * 16 + l15] = f2b(o[i][nt][r] * inv);
    }
}

// ---------------------------------------------------------------------------
// K4: positional-decay attention via separable scans (sinv hoisted).
// ---------------------------------------------------------------------------
__global__ __launch_bounds__(256) void k_band(
    const u16* __restrict__ qkvt, u16* __restrict__ out12) {
  __shared__ float sinv[4][192];
  __shared__ float fbuf[4][64][68];
  const int tid = threadIdx.x;
  const int w = tid >> 6, d = tid & 63;
  const int c  = blockIdx.x * 4 + w;       // chunk 0..31
  const int i0 = c * 64;
  const int bh = blockIdx.y;
  const size_t tb = 3ull * QKS + (size_t)bh * (NSEQ * NDH);
  const float EI = 0.36787944117144233f;   // 1/e
  const float RR = 0.69220062755534635f;   // exp(-1/e)
  const float OMR = 1.f - RR;
#pragma unroll
  for (int p = 0; p < 3; ++p) {
    const int j = i0 - 64 + p * 64 + d;
    const float r1 = __expf(-(float)(j + 1) * EI);
    const float r2 = __expf(-(float)(NSEQ - j) * EI);
    sinv[w][p * 64 + d] = OMR / (1.f - r1 + RR - r2);
  }
  const u16* tp = qkvt + tb + d;
  float f = 0.f;
  if (c > 0) {
#pragma unroll 8
    for (int jj = 0; jj < 64; ++jj)
      f = RR * f + sinv[w][jj] * b2f(tp[(size_t)(i0 - 64 + jj) * NDH]);
  }
#pragma unroll 8
  for (int jj = 0; jj < 64; ++jj) {
    f = RR * f + sinv[w][64 + jj] * b2f(tp[(size_t)(i0 + jj) * NDH]);
    fbuf[w][jj][d] = f;
  }
  float b = 0.f;
  if (c < 31) {
#pragma unroll 8
    for (int jj = 63; jj >= 0; --jj)
      b = RR * b + sinv[w][128 + jj] * b2f(tp[(size_t)(i0 + 64 + jj) * NDH]);
  }
  const int bb = bh >> 3, h = bh & 7;
#pragma unroll 8
  for (int jj = 63; jj >= 0; --jj) {
    const float g = sinv[w][64 + jj] * b2f(tp[(size_t)(i0 + jj) * NDH]);
    b = RR * b + g;
    out12[(size_t)(bb * NSEQ + i0 + jj) * 1024 + h * 128 + 64 + d] =
        f2b(fbuf[w][jj][d] + b - g);
  }
}

// ---------------------------------------------------------------------------
// K3: out = out12[4096,1024](bf16) @ Woutbf[512,1024]^T + bias -> f32 (MFMA).
// ---------------------------------------------------------------------------
__global__ __launch_bounds__(256) void k_gemm_out(
    const u16* __restrict__ A, const u16* __restrict__ W,
    const float* __restrict__ bias, float* __restrict__ out) {
  __shared__ __align__(16) float smemf[8704];  // stage | epi 4x(32x68)f32
  bf16* As = (bf16*)smemf;        // [128][40]
  bf16* Bs = (bf16*)smemf + 5120; // [64][40]
  const int tid = threadIdx.x;
  const int n0 = blockIdx.x * 64;
  const int m0 = blockIdx.y * 128;
  const int w = tid >> 6, lane = tid & 63;
  const int quad = lane >> 4, l15 = lane & 15;
  const int srow = tid >> 1, shalf = (tid & 1) * 16;
  const u16* ap = A + (size_t)(m0 + srow) * 1024 + shalf;
  const int brow = (tid & 127) >> 1;
  const u16* bp = W + (size_t)(n0 + brow) * 1024 + shalf;
  f32x4 acc[2][4];
#pragma unroll
  for (int mt = 0; mt < 2; ++mt)
#pragma unroll
    for (int nt = 0; nt < 4; ++nt) acc[mt][nt] = (f32x4){0.f, 0.f, 0.f, 0.f};
  uint4 a0 = *(const uint4*)ap, a1 = *(const uint4*)(ap + 8);
  uint4 b0 = {}, b1 = {};
  if (tid < 128) { b0 = *(const uint4*)bp; b1 = *(const uint4*)(bp + 8); }
  for (int kc = 0; kc < 1024; kc += 32) {
    __syncthreads();
    *(uint4*)&As[srow * 40 + shalf]     = a0;
    *(uint4*)&As[srow * 40 + shalf + 8] = a1;
    if (tid < 128) {
      *(uint4*)&Bs[brow * 40 + shalf]     = b0;
      *(uint4*)&Bs[brow * 40 + shalf + 8] = b1;
    }
    __syncthreads();
    if (kc + 32 < 1024) {
      a0 = *(const uint4*)(ap + kc + 32);
      a1 = *(const uint4*)(ap + kc + 40);
      if (tid < 128) {
        b0 = *(const uint4*)(bp + kc + 32);
        b1 = *(const uint4*)(bp + kc + 40);
      }
    }
    bf16x8 af[2], bfr[4];
#pragma unroll
    for (int mt = 0; mt < 2; ++mt)
      af[mt] = *(const bf16x8*)&As[(w * 32 + mt * 16 + l15) * 40 + quad * 8];
#pragma unroll
    for (int nt = 0; nt < 4; ++nt)
      bfr[nt] = *(const bf16x8*)&Bs[(nt * 16 + l15) * 40 + quad * 8];
#pragma unroll
    for (int mt = 0; mt < 2; ++mt)
#pragma unroll
      for (int nt = 0; nt < 4; ++nt)
        acc[mt][nt] = __builtin_amdgcn_mfma_f32_16x16x32_bf16(af[mt], bfr[nt], acc[mt][nt], 0, 0, 0);
  }
  float bias_v[4];
#pragma unroll
  for (int nt = 0; nt < 4; ++nt) bias_v[nt] = bias[n0 + nt * 16 + l15];
  __syncthreads();   // staging reads done; reuse smem
  float* Cw = smemf + w * 2176;   // per-wave [32][68]
#pragma unroll
  for (int mt = 0; mt < 2; ++mt)
#pragma unroll
    for (int nt = 0; nt < 4; ++nt)
#pragma unroll
      for (int r = 0; r < 4; ++r)
        Cw[(mt * 16 + quad * 4 + r) * 68 + nt * 16 + l15] = acc[mt][nt][r] + bias_v[nt];
#pragma unroll
  for (int p = 0; p < 8; ++p) {
    const int row = p * 4 + (lane >> 4);
    const int c4  = lane & 15;
    const float4 v = *(const float4*)&Cw[row * 68 + c4 * 4];
    *(float4*)(out + (size_t)(m0 + w * 32 + row) * 512 + n0 + c4 * 4) = v;
  }
}

extern "C" void kernel_launch(void* const* d_in, const int* in_sizes, int n_in,
                              void* d_out, int out_size, void* d_ws, size_t ws_size,
                              hipStream_t stream) {
  (void)in_sizes; (void)n_in; (void)out_size; (void)ws_size;
  const float* x     = (const float*)d_in[0];
  const float* w_qkv = (const float*)d_in[1];
  const float* w_out = (const float*)d_in[2];
  const float* b_out = (const float*)d_in[3];
  float* out = (float*)d_out;
  u16* qkvt    = (u16*)d_ws;
  u16* out12   = (u16*)d_ws + 8ull * 1024 * 1024;
  u16* xbf     = out12;  // overlay: dead until k_attn writes out12
  u16* wqkvbf  = (u16*)d_ws + 10ull * 1024 * 1024;
  u16* woutbf  = (u16*)d_ws + 12ull * 1024 * 1024;
  k_cvt      <<<3584, 256, 0, stream>>>(x, w_qkv, w_out, xbf, wqkvbf, woutbf);
  k_gemm_qkvt<<<dim3(16, 32), 256, 0, stream>>>(xbf, wqkvbf, qkvt);
  k_attn     <<<dim3(16, 32), 128, 0, stream>>>(qkvt, out12);
  k_band     <<<dim3(8, 16), 256, 0, stream>>>(qkvt, out12);
  k_gemm_out <<<dim3(8, 32), 256, 0, stream>>>(out12, woutbf, b_out, out);
}

// Round 10
// 160.443 us; speedup vs baseline: 1.2041x; 1.2041x over previous
//
#include <hip/hip_runtime.h>
#include <stdint.h>

typedef unsigned short u16;
typedef __bf16 bf16;
typedef __bf16 bf16x8 __attribute__((ext_vector_type(8)));
typedef float f32x4 __attribute__((ext_vector_type(4)));

#define NSEQ 2048
#define NDH 64
#define NH 8
#define QKS 2097152ull  // elements per q/k/v/t plane

__device__ __forceinline__ float b2f(u16 u) {
  union { float f; uint32_t i; } x; x.i = ((uint32_t)u) << 16; return x.f;
}
__device__ __forceinline__ u16 f2b(float f) {
  union { float f; uint32_t i; } x; x.f = f;
  const uint32_t r = x.i + 0x7FFFu + ((x.i >> 16) & 1u);
  return (u16)(r >> 16);
}

// ---------------------------------------------------------------------------
// K1: qkvt = X[4096,512](f32) @ Wqkv[2048,512](f32)^T (MFMA 16x16x32 bf16),
// fp32->bf16 conversion fused into staging (no separate cvt kernel).
// q plane pre-scaled by dh^-0.5*log2(e). V plane stored transposed
// [b,h,dim,tok]. LDS-transpose epilogue -> coalesced uint4 stores.
// ---------------------------------------------------------------------------
__global__ __launch_bounds__(256) void k_gemm_qkvt(
    const float* __restrict__ X, const float* __restrict__ W, u16* __restrict__ qkvt) {
  __shared__ __align__(16) bf16 smem[18432];  // stage 10240 | epi 4x(64x72)
  bf16* As = smem;          // [128][40]
  bf16* Bs = smem + 5120;   // [128][40]
  const int tid = threadIdx.x;
  const int n0 = blockIdx.x * 128;
  const int m0 = blockIdx.y * 128;
  const int w = tid >> 6, lane = tid & 63;
  const int wy = w >> 1, wx = w & 1;
  const int quad = lane >> 4, l15 = lane & 15;
  const int srow = tid >> 1, shalf = (tid & 1) * 16;
  const float* ax = X + (size_t)(m0 + srow) * 512 + shalf;
  const float* bx = W + (size_t)(n0 + srow) * 512 + shalf;
  f32x4 acc[4][4];
#pragma unroll
  for (int mt = 0; mt < 4; ++mt)
#pragma unroll
    for (int nt = 0; nt < 4; ++nt) acc[mt][nt] = (f32x4){0.f, 0.f, 0.f, 0.f};
  float4 af[4], bf4[4];
#pragma unroll
  for (int p = 0; p < 4; ++p) {
    af[p]  = *(const float4*)(ax + p * 4);
    bf4[p] = *(const float4*)(bx + p * 4);
  }
  for (int kc = 0; kc < 512; kc += 32) {
    __syncthreads();
    {
      u16 ta[8] = {f2b(af[0].x), f2b(af[0].y), f2b(af[0].z), f2b(af[0].w),
                   f2b(af[1].x), f2b(af[1].y), f2b(af[1].z), f2b(af[1].w)};
      u16 tb[8] = {f2b(af[2].x), f2b(af[2].y), f2b(af[2].z), f2b(af[2].w),
                   f2b(af[3].x), f2b(af[3].y), f2b(af[3].z), f2b(af[3].w)};
      *(uint4*)&As[srow * 40 + shalf]     = *(const uint4*)ta;
      *(uint4*)&As[srow * 40 + shalf + 8] = *(const uint4*)tb;
      u16 tc[8] = {f2b(bf4[0].x), f2b(bf4[0].y), f2b(bf4[0].z), f2b(bf4[0].w),
                   f2b(bf4[1].x), f2b(bf4[1].y), f2b(bf4[1].z), f2b(bf4[1].w)};
      u16 td[8] = {f2b(bf4[2].x), f2b(bf4[2].y), f2b(bf4[2].z), f2b(bf4[2].w),
                   f2b(bf4[3].x), f2b(bf4[3].y), f2b(bf4[3].z), f2b(bf4[3].w)};
      *(uint4*)&Bs[srow * 40 + shalf]     = *(const uint4*)tc;
      *(uint4*)&Bs[srow * 40 + shalf + 8] = *(const uint4*)td;
    }
    __syncthreads();
    if (kc + 32 < 512) {
#pragma unroll
      for (int p = 0; p < 4; ++p) {
        af[p]  = *(const float4*)(ax + kc + 32 + p * 4);
        bf4[p] = *(const float4*)(bx + kc + 32 + p * 4);
      }
    }
    bf16x8 afr[4], bfr[4];
#pragma unroll
    for (int mt = 0; mt < 4; ++mt)
      afr[mt] = *(const bf16x8*)&As[(wy * 64 + mt * 16 + l15) * 40 + quad * 8];
#pragma unroll
    for (int nt = 0; nt < 4; ++nt)
      bfr[nt] = *(const bf16x8*)&Bs[(wx * 64 + nt * 16 + l15) * 40 + quad * 8];
#pragma unroll
    for (int mt = 0; mt < 4; ++mt)
#pragma unroll
      for (int nt = 0; nt < 4; ++nt)
        acc[mt][nt] = __builtin_amdgcn_mfma_f32_16x16x32_bf16(afr[mt], bfr[nt], acc[mt][nt], 0, 0, 0);
  }
  __syncthreads();   // staging reads done; reuse smem for epilogue
  const int cbase = n0 + wx * 64;
  const int which = cbase >> 9;       // 0=q 1=k 2=v 3=t
  const int h     = (cbase >> 6) & 7;
  // q scale: dh^-0.5 * log2(e) so attention exp is raw exp2
  const float scale = (which == 0) ? 0.18033688011112043f : 1.0f;
  bf16* Cw = smem + w * 4608;         // per-wave [64][72]
  if (which == 2) {
#pragma unroll
    for (int nt = 0; nt < 4; ++nt)
#pragma unroll
      for (int mt = 0; mt < 4; ++mt)
#pragma unroll
        for (int r = 0; r < 4; ++r)
          Cw[(nt * 16 + l15) * 72 + mt * 16 + quad * 4 + r] = (bf16)acc[mt][nt][r];
  } else {
#pragma unroll
    for (int mt = 0; mt < 4; ++mt)
#pragma unroll
      for (int nt = 0; nt < 4; ++nt)
#pragma unroll
        for (int r = 0; r < 4; ++r)
          Cw[(mt * 16 + quad * 4 + r) * 72 + nt * 16 + l15] = (bf16)(acc[mt][nt][r] * scale);
  }
  const int mb = m0 + wy * 64;
  const int bb = mb >> 11;
  const int nn0 = mb & (NSEQ - 1);
  if (which == 2) {
    u16* vt = qkvt + 2ull * QKS + (size_t)(bb * NH + h) * NDH * NSEQ;
#pragma unroll
    for (int p = 0; p < 8; ++p) {
      const int d = p * 8 + (lane >> 3);
      const int t8 = (lane & 7) * 8;
      const uint4 v = *(const uint4*)&Cw[d * 72 + t8];
      *(uint4*)(vt + (size_t)d * NSEQ + nn0 + t8) = v;
    }
  } else {
    u16* dst = qkvt + (size_t)which * QKS + ((size_t)(bb * NH + h) * NSEQ + nn0) * NDH;
#pragma unroll
    for (int p = 0; p < 8; ++p) {
      const int tok = p * 8 + (lane >> 3);
      const int c8 = (lane & 7) * 8;
      const uint4 v = *(const uint4*)&Cw[tok * 72 + c8];
      *(uint4*)(dst + (size_t)tok * NDH + c8) = v;
    }
  }
}

// ---------------------------------------------------------------------------
// K2: MFMA flash attention — R7 structure (256 thr, 16 q/wave, 512 blocks,
// 8 waves/CU) + Pw stride 76 (write conflicts <=2-way) + XCD-swizzled grid
// (bh in x: one bh's K/V stays on one XCD's L2). No-max softmax via exp2,
// l via ones-column MFMA.
// ---------------------------------------------------------------------------
__global__ __launch_bounds__(256) void k_attn(
    const u16* __restrict__ qkvt, u16* __restrict__ out12) {
  __shared__ __align__(16) bf16 Qs[64][72];
  __shared__ __align__(16) bf16 Ks[64][72];
  __shared__ __align__(16) bf16 Vt[64][72];   // [dim][key]
  __shared__ __align__(16) bf16 Pw[64][76];   // per-wave 16-row regions
  const int tid = threadIdx.x;
  const int bh  = blockIdx.x;
  const int q0  = blockIdx.y * 64;
  const size_t base  = (size_t)bh * (NSEQ * NDH);
  const size_t vbase = 2ull * QKS + (size_t)bh * (NDH * NSEQ);
  const int wq = tid >> 6, lane = tid & 63;
  const int quad = lane >> 4, l15 = lane & 15;
  const int srow = tid >> 2, sc0 = (tid & 3) * 16;
  {
    const u16* qp = qkvt + base + (size_t)(q0 + srow) * NDH + sc0;
    *(uint4*)&Qs[srow][sc0]     = *(const uint4*)qp;
    *(uint4*)&Qs[srow][sc0 + 8] = *(const uint4*)(qp + 8);
  }
  __syncthreads();
  const bf16x8 qa0 = *(const bf16x8*)&Qs[wq * 16 + l15][quad * 8];
  const bf16x8 qa1 = *(const bf16x8*)&Qs[wq * 16 + l15][32 + quad * 8];
  bf16x8 vones;
#pragma unroll
  for (int j = 0; j < 8; ++j) vones[j] = (l15 == 0) ? (bf16)1.f : (bf16)0.f;
  f32x4 lacc = {0.f, 0.f, 0.f, 0.f};
  f32x4 o[4] = {{0.f,0.f,0.f,0.f},{0.f,0.f,0.f,0.f},{0.f,0.f,0.f,0.f},{0.f,0.f,0.f,0.f}};
  const u16* kp = qkvt + QKS + base + (size_t)srow * NDH + sc0;
  const u16* vp = qkvt + vbase + (size_t)srow * NSEQ + sc0;
  uint4 k0 = *(const uint4*)kp;
  uint4 k1 = *(const uint4*)(kp + 8);
  uint4 v0 = *(const uint4*)vp;
  uint4 v1 = *(const uint4*)(vp + 8);
  for (int kt = 0; kt < 32; ++kt) {
    __syncthreads();
    *(uint4*)&Ks[srow][sc0]     = k0;
    *(uint4*)&Ks[srow][sc0 + 8] = k1;
    *(uint4*)&Vt[srow][sc0]     = v0;
    *(uint4*)&Vt[srow][sc0 + 8] = v1;
    __syncthreads();
    if (kt < 31) {   // prefetch next tile during compute
      const u16* kn = kp + (size_t)(kt + 1) * 64 * NDH;
      const u16* vn = vp + (kt + 1) * 64;
      k0 = *(const uint4*)kn;
      k1 = *(const uint4*)(kn + 8);
      v0 = *(const uint4*)vn;
      v1 = *(const uint4*)(vn + 8);
    }
    f32x4 s[4] = {{0.f,0.f,0.f,0.f},{0.f,0.f,0.f,0.f},{0.f,0.f,0.f,0.f},{0.f,0.f,0.f,0.f}};
#pragma unroll
    for (int t = 0; t < 4; ++t) {
      const bf16x8 kb0 = *(const bf16x8*)&Ks[t * 16 + l15][quad * 8];
      const bf16x8 kb1 = *(const bf16x8*)&Ks[t * 16 + l15][32 + quad * 8];
      s[t] = __builtin_amdgcn_mfma_f32_16x16x32_bf16(qa0, kb0, s[t], 0, 0, 0);
      s[t] = __builtin_amdgcn_mfma_f32_16x16x32_bf16(qa1, kb1, s[t], 0, 0, 0);
    }
    // p = exp2(s); P -> per-wave LDS region (stride 76)
#pragma unroll
    for (int r = 0; r < 4; ++r) {
      const int prow = wq * 16 + quad * 4 + r;
      Pw[prow][l15]      = (bf16)__builtin_amdgcn_exp2f(s[0][r]);
      Pw[prow][16 + l15] = (bf16)__builtin_amdgcn_exp2f(s[1][r]);
      Pw[prow][32 + l15] = (bf16)__builtin_amdgcn_exp2f(s[2][r]);
      Pw[prow][48 + l15] = (bf16)__builtin_amdgcn_exp2f(s[3][r]);
    }
    // wave-local P region: no barrier needed before re-read
#pragma unroll
    for (int c = 0; c < 2; ++c) {
      const bf16x8 pa = *(const bf16x8*)&Pw[wq * 16 + l15][c * 32 + quad * 8];
      lacc = __builtin_amdgcn_mfma_f32_16x16x32_bf16(pa, vones, lacc, 0, 0, 0);
#pragma unroll
      for (int nt = 0; nt < 4; ++nt) {
        const bf16x8 vb = *(const bf16x8*)&Vt[nt * 16 + l15][c * 32 + quad * 8];
        o[nt] = __builtin_amdgcn_mfma_f32_16x16x32_bf16(pa, vb, o[nt], 0, 0, 0);
      }
    }
  }
  const int bb = bh >> 3, h = bh & 7;
#pragma unroll
  for (int r = 0; r < 4; ++r) {
    const float lsum = __shfl(lacc[r], lane & 48);  // col 0 of my quad's rows
    const float inv = 1.f / lsum;
    const int nn = q0 + wq * 16 + quad * 4 + r;
    u16* dst = out12 + (size_t)(bb * NSEQ + nn) * 1024 + h * 128;
#pragma unroll
    for (int nt = 0; nt < 4; ++nt)
      dst[nt * 16 + l15] = f2b(o[nt][r] * inv);
  }
}

// ---------------------------------------------------------------------------
// K4: positional-decay attention via separable scans (sinv hoisted).
// ---------------------------------------------------------------------------
__global__ __launch_bounds__(256) void k_band(
    const u16* __restrict__ qkvt, u16* __restrict__ out12) {
  __shared__ float sinv[4][192];
  __shared__ float fbuf[4][64][68];
  const int tid = threadIdx.x;
  const int w = tid >> 6, d = tid & 63;
  const int c  = blockIdx.x * 4 + w;       // chunk 0..31
  const int i0 = c * 64;
  const int bh = blockIdx.y;
  const size_t tb = 3ull * QKS + (size_t)bh * (NSEQ * NDH);
  const float EI = 0.36787944117144233f;   // 1/e
  const float RR = 0.69220062755534635f;   // exp(-1/e)
  const float OMR = 1.f - RR;
#pragma unroll
  for (int p = 0; p < 3; ++p) {
    const int j = i0 - 64 + p * 64 + d;
    const float r1 = __expf(-(float)(j + 1) * EI);
    const float r2 = __expf(-(float)(NSEQ - j) * EI);
    sinv[w][p * 64 + d] = OMR / (1.f - r1 + RR - r2);
  }
  const u16* tp = qkvt + tb + d;
  float f = 0.f;
  if (c > 0) {
#pragma unroll 8
    for (int jj = 0; jj < 64; ++jj)
      f = RR * f + sinv[w][jj] * b2f(tp[(size_t)(i0 - 64 + jj) * NDH]);
  }
#pragma unroll 8
  for (int jj = 0; jj < 64; ++jj) {
    f = RR * f + sinv[w][64 + jj] * b2f(tp[(size_t)(i0 + jj) * NDH]);
    fbuf[w][jj][d] = f;
  }
  float b = 0.f;
  if (c < 31) {
#pragma unroll 8
    for (int jj = 63; jj >= 0; --jj)
      b = RR * b + sinv[w][128 + jj] * b2f(tp[(size_t)(i0 + 64 + jj) * NDH]);
  }
  const int bb = bh >> 3, h = bh & 7;
#pragma unroll 8
  for (int jj = 63; jj >= 0; --jj) {
    const float g = sinv[w][64 + jj] * b2f(tp[(size_t)(i0 + jj) * NDH]);
    b = RR * b + g;
    out12[(size_t)(bb * NSEQ + i0 + jj) * 1024 + h * 128 + 64 + d] =
        f2b(fbuf[w][jj][d] + b - g);
  }
}

// ---------------------------------------------------------------------------
// K3: out = out12[4096,1024](bf16) @ Wout[512,1024](f32)^T + bias -> f32.
// 64x64 tiles, BK=32, grid 512 blocks (2+/CU). W cvt fused into staging.
// ---------------------------------------------------------------------------
__global__ __launch_bounds__(256) void k_gemm_out(
    const u16* __restrict__ A, const float* __restrict__ W,
    const float* __restrict__ bias, float* __restrict__ out) {
  __shared__ __align__(16) float smemf[4352];  // stage 10240B | epi 4x(16x68)f32
  bf16* As = (bf16*)smemf;         // [64][40]
  bf16* Bs = (bf16*)smemf + 2560;  // [64][40]
  const int tid = threadIdx.x;
  const int n0 = blockIdx.x * 64;
  const int m0 = blockIdx.y * 64;
  const int w = tid >> 6, lane = tid & 63;
  const int quad = lane >> 4, l15 = lane & 15;
  const int srow = tid >> 2, scol = (tid & 3) * 8;
  const u16*   ap = A + (size_t)(m0 + srow) * 1024 + scol;
  const float* bp = W + (size_t)(n0 + srow) * 1024 + scol;
  f32x4 acc[4];
#pragma unroll
  for (int nt = 0; nt < 4; ++nt) acc[nt] = (f32x4){0.f, 0.f, 0.f, 0.f};
  uint4 a0 = *(const uint4*)ap;
  float4 b0 = *(const float4*)bp;
  float4 b1 = *(const float4*)(bp + 4);
  for (int kc = 0; kc < 1024; kc += 32) {
    __syncthreads();
    *(uint4*)&As[srow * 40 + scol] = a0;
    {
      u16 tb[8] = {f2b(b0.x), f2b(b0.y), f2b(b0.z), f2b(b0.w),
                   f2b(b1.x), f2b(b1.y), f2b(b1.z), f2b(b1.w)};
      *(uint4*)&Bs[srow * 40 + scol] = *(const uint4*)tb;
    }
    __syncthreads();
    if (kc + 32 < 1024) {
      a0 = *(const uint4*)(ap + kc + 32);
      b0 = *(const float4*)(bp + kc + 32);
      b1 = *(const float4*)(bp + kc + 36);
    }
    const bf16x8 af = *(const bf16x8*)&As[(w * 16 + l15) * 40 + quad * 8];
#pragma unroll
    for (int nt = 0; nt < 4; ++nt) {
      const bf16x8 bfr = *(const bf16x8*)&Bs[(nt * 16 + l15) * 40 + quad * 8];
      acc[nt] = __builtin_amdgcn_mfma_f32_16x16x32_bf16(af, bfr, acc[nt], 0, 0, 0);
    }
  }
  float bias_v[4];
#pragma unroll
  for (int nt = 0; nt < 4; ++nt) bias_v[nt] = bias[n0 + nt * 16 + l15];
  __syncthreads();   // staging reads done; reuse smem
  float* Cw = smemf + w * 1088;   // per-wave [16][68]
#pragma unroll
  for (int nt = 0; nt < 4; ++nt)
#pragma unroll
    for (int r = 0; r < 4; ++r)
      Cw[(quad * 4 + r) * 68 + nt * 16 + l15] = acc[nt][r] + bias_v[nt];
  // wave-local: no barrier
#pragma unroll
  for (int p = 0; p < 4; ++p) {
    const int row = p * 4 + (lane >> 4);
    const int c4  = (lane & 15) * 4;
    const float4 v = *(const float4*)&Cw[row * 68 + c4];
    *(float4*)(out + (size_t)(m0 + w * 16 + row) * 512 + n0 + c4) = v;
  }
}

extern "C" void kernel_launch(void* const* d_in, const int* in_sizes, int n_in,
                              void* d_out, int out_size, void* d_ws, size_t ws_size,
                              hipStream_t stream) {
  (void)in_sizes; (void)n_in; (void)out_size; (void)ws_size;
  const float* x     = (const float*)d_in[0];
  const float* w_qkv = (const float*)d_in[1];
  const float* w_out = (const float*)d_in[2];
  const float* b_out = (const float*)d_in[3];
  float* out = (float*)d_out;
  u16* qkvt  = (u16*)d_ws;                          // [0, 16M)
  u16* out12 = (u16*)d_ws + 8ull * 1024 * 1024;     // [16M, 24M)
  k_gemm_qkvt<<<dim3(16, 32), 256, 0, stream>>>(x, w_qkv, qkvt);
  k_attn     <<<dim3(16, 32), 256, 0, stream>>>(qkvt, out12);
  k_band     <<<dim3(8, 16), 256, 0, stream>>>(qkvt, out12);
  k_gemm_out <<<dim3(8, 64), 256, 0, stream>>>(out12, w_out, b_out, out);
}

// Round 11
// 149.580 us; speedup vs baseline: 1.2916x; 1.0726x over previous
//
#include <hip/hip_runtime.h>
#include <hip/hip_bf16.h>
#include <stdint.h>

typedef unsigned short u16;
typedef __bf16 bf16;
typedef __bf16 bf16x8 __attribute__((ext_vector_type(8)));
typedef float f32x4 __attribute__((ext_vector_type(4)));
typedef float f32x16 __attribute__((ext_vector_type(16)));

#define NSEQ 2048
#define NDH 64
#define NH 8
#define QKS 2097152ull  // elements per q/k/v/t plane

__device__ __forceinline__ float b2f(u16 u) {
  union { float f; uint32_t i; } x; x.i = ((uint32_t)u) << 16; return x.f;
}
__device__ __forceinline__ u16 f2b(float f) {
  union { float f; uint32_t i; } x; x.f = f;
  const uint32_t r = x.i + 0x7FFFu + ((x.i >> 16) & 1u);
  return (u16)(r >> 16);
}
// packed f32x2 -> bf16x2 (RNE, v_cvt_pk path)
__device__ __forceinline__ uint32_t b2pk(float a, float b) {
  union { __hip_bfloat162 h; uint32_t u; } x;
  x.h = __float22bfloat162_rn(make_float2(a, b));
  return x.u;
}

// ---------------------------------------------------------------------------
// K1: qkvt = X[4096,512](f32) @ Wqkv[2048,512](f32)^T (MFMA 16x16x32 bf16),
// fp32->bf16 cvt fused into staging via packed converts.
// q plane pre-scaled by dh^-0.5*log2(e). V plane stored transposed
// [b,h,dim,tok]. LDS-transpose epilogue -> coalesced uint4 stores.
// ---------------------------------------------------------------------------
__global__ __launch_bounds__(256) void k_gemm_qkvt(
    const float* __restrict__ X, const float* __restrict__ W, u16* __restrict__ qkvt) {
  __shared__ __align__(16) bf16 smem[18432];  // stage 10240 | epi 4x(64x72)
  bf16* As = smem;          // [128][40]
  bf16* Bs = smem + 5120;   // [128][40]
  const int tid = threadIdx.x;
  const int n0 = blockIdx.x * 128;
  const int m0 = blockIdx.y * 128;
  const int w = tid >> 6, lane = tid & 63;
  const int wy = w >> 1, wx = w & 1;
  const int quad = lane >> 4, l15 = lane & 15;
  const int srow = tid >> 1, shalf = (tid & 1) * 16;
  const float* ax = X + (size_t)(m0 + srow) * 512 + shalf;
  const float* bx = W + (size_t)(n0 + srow) * 512 + shalf;
  f32x4 acc[4][4];
#pragma unroll
  for (int mt = 0; mt < 4; ++mt)
#pragma unroll
    for (int nt = 0; nt < 4; ++nt) acc[mt][nt] = (f32x4){0.f, 0.f, 0.f, 0.f};
  float4 af[4], bf4[4];
#pragma unroll
  for (int p = 0; p < 4; ++p) {
    af[p]  = *(const float4*)(ax + p * 4);
    bf4[p] = *(const float4*)(bx + p * 4);
  }
  for (int kc = 0; kc < 512; kc += 32) {
    __syncthreads();
    {
      uint4 ta = {b2pk(af[0].x, af[0].y), b2pk(af[0].z, af[0].w),
                  b2pk(af[1].x, af[1].y), b2pk(af[1].z, af[1].w)};
      uint4 tb = {b2pk(af[2].x, af[2].y), b2pk(af[2].z, af[2].w),
                  b2pk(af[3].x, af[3].y), b2pk(af[3].z, af[3].w)};
      *(uint4*)&As[srow * 40 + shalf]     = ta;
      *(uint4*)&As[srow * 40 + shalf + 8] = tb;
      uint4 tc = {b2pk(bf4[0].x, bf4[0].y), b2pk(bf4[0].z, bf4[0].w),
                  b2pk(bf4[1].x, bf4[1].y), b2pk(bf4[1].z, bf4[1].w)};
      uint4 td = {b2pk(bf4[2].x, bf4[2].y), b2pk(bf4[2].z, bf4[2].w),
                  b2pk(bf4[3].x, bf4[3].y), b2pk(bf4[3].z, bf4[3].w)};
      *(uint4*)&Bs[srow * 40 + shalf]     = tc;
      *(uint4*)&Bs[srow * 40 + shalf + 8] = td;
    }
    __syncthreads();
    if (kc + 32 < 512) {
#pragma unroll
      for (int p = 0; p < 4; ++p) {
        af[p]  = *(const float4*)(ax + kc + 32 + p * 4);
        bf4[p] = *(const float4*)(bx + kc + 32 + p * 4);
      }
    }
    bf16x8 afr[4], bfr[4];
#pragma unroll
    for (int mt = 0; mt < 4; ++mt)
      afr[mt] = *(const bf16x8*)&As[(wy * 64 + mt * 16 + l15) * 40 + quad * 8];
#pragma unroll
    for (int nt = 0; nt < 4; ++nt)
      bfr[nt] = *(const bf16x8*)&Bs[(wx * 64 + nt * 16 + l15) * 40 + quad * 8];
#pragma unroll
    for (int mt = 0; mt < 4; ++mt)
#pragma unroll
      for (int nt = 0; nt < 4; ++nt)
        acc[mt][nt] = __builtin_amdgcn_mfma_f32_16x16x32_bf16(afr[mt], bfr[nt], acc[mt][nt], 0, 0, 0);
  }
  __syncthreads();   // staging reads done; reuse smem for epilogue
  const int cbase = n0 + wx * 64;
  const int which = cbase >> 9;       // 0=q 1=k 2=v 3=t
  const int h     = (cbase >> 6) & 7;
  // q scale: dh^-0.5 * log2(e) so attention exp is raw exp2
  const float scale = (which == 0) ? 0.18033688011112043f : 1.0f;
  bf16* Cw = smem + w * 4608;         // per-wave [64][72]
  if (which == 2) {
#pragma unroll
    for (int nt = 0; nt < 4; ++nt)
#pragma unroll
      for (int mt = 0; mt < 4; ++mt)
#pragma unroll
        for (int r = 0; r < 4; ++r)
          Cw[(nt * 16 + l15) * 72 + mt * 16 + quad * 4 + r] = (bf16)acc[mt][nt][r];
  } else {
#pragma unroll
    for (int mt = 0; mt < 4; ++mt)
#pragma unroll
      for (int nt = 0; nt < 4; ++nt)
#pragma unroll
        for (int r = 0; r < 4; ++r)
          Cw[(mt * 16 + quad * 4 + r) * 72 + nt * 16 + l15] = (bf16)(acc[mt][nt][r] * scale);
  }
  const int mb = m0 + wy * 64;
  const int bb = mb >> 11;
  const int nn0 = mb & (NSEQ - 1);
  if (which == 2) {
    u16* vt = qkvt + 2ull * QKS + (size_t)(bb * NH + h) * NDH * NSEQ;
#pragma unroll
    for (int p = 0; p < 8; ++p) {
      const int d = p * 8 + (lane >> 3);
      const int t8 = (lane & 7) * 8;
      const uint4 v = *(const uint4*)&Cw[d * 72 + t8];
      *(uint4*)(vt + (size_t)d * NSEQ + nn0 + t8) = v;
    }
  } else {
    u16* dst = qkvt + (size_t)which * QKS + ((size_t)(bb * NH + h) * NSEQ + nn0) * NDH;
#pragma unroll
    for (int p = 0; p < 8; ++p) {
      const int tok = p * 8 + (lane >> 3);
      const int c8 = (lane & 7) * 8;
      const uint4 v = *(const uint4*)&Cw[tok * 72 + c8];
      *(uint4*)(dst + (size_t)tok * NDH + c8) = v;
    }
  }
}

// ---------------------------------------------------------------------------
// K2: MFMA flash attention, 32x32x16 key-split design.
// Block 256 thr = 4 waves (qh = wq>>1: 32 queries; kh = wq&1: 32-key half of
// each staged 64-key tile). S^T = mfma(A=K, B=Q): C-layout gives query=lane&31,
// keys=16 regs -> l is in-lane VALU + shfl_xor(32); P-writes are 4x b64
// (consecutive keys); P lands in A-layout for PV (b128 reads). Cross-wave
// O/l merge once at epilogue (no-max softmax => plain add). exp2 with scale
// pre-folded into q plane. Grid (bh, qtile) for XCD L2 locality.
// ---------------------------------------------------------------------------
__global__ __launch_bounds__(256) void k_attn(
    const u16* __restrict__ qkvt, u16* __restrict__ out12) {
  __shared__ __align__(16) bf16 Qs[64 * 72];
  __shared__ __align__(16) bf16 KV[2 * 64 * 72];   // Ks | Vt ; epilogue: Osum f32[2][32][64]
  __shared__ __align__(16) bf16 Pw[4 * 32 * 72];   // per-wave [32 q][72]
  __shared__ float Lpart[4][32];
  bf16* Ks = KV;
  bf16* Vt = KV + 64 * 72;
  const int tid = threadIdx.x;
  const int bh  = blockIdx.x;
  const int q0  = blockIdx.y * 64;
  const size_t base  = (size_t)bh * (NSEQ * NDH);
  const size_t vbase = 2ull * QKS + (size_t)bh * (NDH * NSEQ);
  const int wq = tid >> 6, lane = tid & 63;
  const int qh = wq >> 1, kh = wq & 1;
  const int l31 = lane & 31, hi = lane >> 5;
  const int srow = tid >> 2, sc0 = (tid & 3) * 16;
  { // stage 64 Q rows [token][dim]
    const u16* qp = qkvt + base + (size_t)(q0 + srow) * NDH + sc0;
    *(uint4*)&Qs[srow * 72 + sc0]     = *(const uint4*)qp;
    *(uint4*)&Qs[srow * 72 + sc0 + 8] = *(const uint4*)(qp + 8);
  }
  __syncthreads();
  // Q B-frags (loop-invariant): B[n=q=l31][k=dim chunk]
  bf16x8 qb[4];
#pragma unroll
  for (int c = 0; c < 4; ++c)
    qb[c] = *(const bf16x8*)&Qs[(qh * 32 + l31) * 72 + c * 16 + hi * 8];
  float lacc = 0.f;
  f32x16 o[2];
#pragma unroll
  for (int nt = 0; nt < 2; ++nt)
#pragma unroll
    for (int r = 0; r < 16; ++r) o[nt][r] = 0.f;
  const u16* kp = qkvt + QKS + base + (size_t)srow * NDH + sc0;
  const u16* vp = qkvt + vbase + (size_t)srow * NSEQ + sc0;
  uint4 k0 = *(const uint4*)kp;
  uint4 k1 = *(const uint4*)(kp + 8);
  uint4 v0 = *(const uint4*)vp;
  uint4 v1 = *(const uint4*)(vp + 8);
  for (int kt = 0; kt < 32; ++kt) {
    __syncthreads();
    *(uint4*)&Ks[srow * 72 + sc0]     = k0;
    *(uint4*)&Ks[srow * 72 + sc0 + 8] = k1;
    *(uint4*)&Vt[srow * 72 + sc0]     = v0;
    *(uint4*)&Vt[srow * 72 + sc0 + 8] = v1;
    __syncthreads();
    if (kt < 31) {   // prefetch next tile during compute
      const u16* kn = kp + (size_t)(kt + 1) * 64 * NDH;
      const u16* vn = vp + (kt + 1) * 64;
      k0 = *(const uint4*)kn;
      k1 = *(const uint4*)(kn + 8);
      v0 = *(const uint4*)vn;
      v1 = *(const uint4*)(vn + 8);
    }
    // S^T: D[m=key_loc][n=q], A = K rows (my key half), B = Q (cached)
    f32x16 s;
#pragma unroll
    for (int r = 0; r < 16; ++r) s[r] = 0.f;
#pragma unroll
    for (int c = 0; c < 4; ++c) {
      const bf16x8 ka = *(const bf16x8*)&Ks[(kh * 32 + l31) * 72 + c * 16 + hi * 8];
      s = __builtin_amdgcn_mfma_f32_32x32x16_bf16(ka, qb[c], s, 0, 0, 0);
    }
    // softmax: p = exp2(s); per-query l: in-lane + shfl_xor(32)
    float ts = 0.f;
#pragma unroll
    for (int r = 0; r < 16; ++r) {
      s[r] = __builtin_amdgcn_exp2f(s[r]);
      ts += s[r];
    }
    ts += __shfl_xor(ts, 32);
    lacc += ts;
    // P[q=l31][key_loc]: C rows = keys (r&3)+8*(r>>2)+4*hi -> b64 packs
    bf16* pr = Pw + (wq * 32 + l31) * 72;
#pragma unroll
    for (int g = 0; g < 4; ++g) {
      bf16 pk[4] = {(bf16)s[4 * g], (bf16)s[4 * g + 1],
                    (bf16)s[4 * g + 2], (bf16)s[4 * g + 3]};
      *(uint2*)&pr[g * 8 + hi * 4] = *(const uint2*)pk;
    }
    // PV: A = P[m=q][k=key_loc] (wave-local, no barrier), B = Vt[n=d][k]
#pragma unroll
    for (int c = 0; c < 2; ++c) {
      const bf16x8 pa = *(const bf16x8*)&Pw[(wq * 32 + l31) * 72 + c * 16 + hi * 8];
      const bf16x8 vb0 = *(const bf16x8*)&Vt[l31 * 72 + kh * 32 + c * 16 + hi * 8];
      const bf16x8 vb1 = *(const bf16x8*)&Vt[(32 + l31) * 72 + kh * 32 + c * 16 + hi * 8];
      o[0] = __builtin_amdgcn_mfma_f32_32x32x16_bf16(pa, vb0, o[0], 0, 0, 0);
      o[1] = __builtin_amdgcn_mfma_f32_32x32x16_bf16(pa, vb1, o[1], 0, 0, 0);
    }
  }
  __syncthreads();   // all Vt reads done; overlay Osum on KV
  if (lane < 32) Lpart[wq][lane] = lacc;
  float* Osum = (float*)KV;   // [2][32][64]
  if (kh == 1) {
#pragma unroll
    for (int nt = 0; nt < 2; ++nt)
#pragma unroll
      for (int r = 0; r < 16; ++r) {
        const int row = (r & 3) + 8 * (r >> 2) + 4 * hi;
        Osum[(qh * 32 + row) * 64 + nt * 32 + l31] = o[nt][r];
      }
  }
  __syncthreads();
  if (kh == 0) {
    const int bb = bh >> 3, h = bh & 7;
#pragma unroll
    for (int r = 0; r < 16; ++r) {
      const int row = (r & 3) + 8 * (r >> 2) + 4 * hi;
      const float lt = Lpart[qh * 2][row] + Lpart[qh * 2 + 1][row];
      const float inv = 1.f / lt;
      const int nn = q0 + qh * 32 + row;
      u16* dst = out12 + (size_t)(bb * NSEQ + nn) * 1024 + h * 128;
      dst[l31]      = f2b((o[0][r] + Osum[(qh * 32 + row) * 64 + l31]) * inv);
      dst[32 + l31] = f2b((o[1][r] + Osum[(qh * 32 + row) * 64 + 32 + l31]) * inv);
    }
  }
}

// ---------------------------------------------------------------------------
// K4: positional-decay attention via separable scans (sinv hoisted).
// ---------------------------------------------------------------------------
__global__ __launch_bounds__(256) void k_band(
    const u16* __restrict__ qkvt, u16* __restrict__ out12) {
  __shared__ float sinv[4][192];
  __shared__ float fbuf[4][64][68];
  const int tid = threadIdx.x;
  const int w = tid >> 6, d = tid & 63;
  const int c  = blockIdx.x * 4 + w;       // chunk 0..31
  const int i0 = c * 64;
  const int bh = blockIdx.y;
  const size_t tb = 3ull * QKS + (size_t)bh * (NSEQ * NDH);
  const float EI = 0.36787944117144233f;   // 1/e
  const float RR = 0.69220062755534635f;   // exp(-1/e)
  const float OMR = 1.f - RR;
#pragma unroll
  for (int p = 0; p < 3; ++p) {
    const int j = i0 - 64 + p * 64 + d;
    const float r1 = __expf(-(float)(j + 1) * EI);
    const float r2 = __expf(-(float)(NSEQ - j) * EI);
    sinv[w][p * 64 + d] = OMR / (1.f - r1 + RR - r2);
  }
  const u16* tp = qkvt + tb + d;
  float f = 0.f;
  if (c > 0) {
#pragma unroll 8
    for (int jj = 0; jj < 64; ++jj)
      f = RR * f + sinv[w][jj] * b2f(tp[(size_t)(i0 - 64 + jj) * NDH]);
  }
#pragma unroll 8
  for (int jj = 0; jj < 64; ++jj) {
    f = RR * f + sinv[w][64 + jj] * b2f(tp[(size_t)(i0 + jj) * NDH]);
    fbuf[w][jj][d] = f;
  }
  float b = 0.f;
  if (c < 31) {
#pragma unroll 8
    for (int jj = 63; jj >= 0; --jj)
      b = RR * b + sinv[w][128 + jj] * b2f(tp[(size_t)(i0 + 64 + jj) * NDH]);
  }
  const int bb = bh >> 3, h = bh & 7;
#pragma unroll 8
  for (int jj = 63; jj >= 0; --jj) {
    const float g = sinv[w][64 + jj] * b2f(tp[(size_t)(i0 + jj) * NDH]);
    b = RR * b + g;
    out12[(size_t)(bb * NSEQ + i0 + jj) * 1024 + h * 128 + 64 + d] =
        f2b(fbuf[w][jj][d] + b - g);
  }
}

// ---------------------------------------------------------------------------
// K3: out = out12[4096,1024](bf16) @ Wout[512,1024](f32)^T + bias -> f32.
// 64x64 tiles, BK=32, grid 512 blocks. W cvt fused (packed converts).
// ---------------------------------------------------------------------------
__global__ __launch_bounds__(256) void k_gemm_out(
    const u16* __restrict__ A, const float* __restrict__ W,
    const float* __restrict__ bias, float* __restrict__ out) {
  __shared__ __align__(16) float smemf[4352];  // stage 10240B | epi 4x(16x68)f32
  bf16* As = (bf16*)smemf;         // [64][40]
  bf16* Bs = (bf16*)smemf + 2560;  // [64][40]
  const int tid = threadIdx.x;
  const int n0 = blockIdx.x * 64;
  const int m0 = blockIdx.y * 64;
  const int w = tid >> 6, lane = tid & 63;
  const int quad = lane >> 4, l15 = lane & 15;
  const int srow = tid >> 2, scol = (tid & 3) * 8;
  const u16*   ap = A + (size_t)(m0 + srow) * 1024 + scol;
  const float* bp = W + (size_t)(n0 + srow) * 1024 + scol;
  f32x4 acc[4];
#pragma unroll
  for (int nt = 0; nt < 4; ++nt) acc[nt] = (f32x4){0.f, 0.f, 0.f, 0.f};
  uint4 a0 = *(const uint4*)ap;
  float4 b0 = *(const float4*)bp;
  float4 b1 = *(const float4*)(bp + 4);
  for (int kc = 0; kc < 1024; kc += 32) {
    __syncthreads();
    *(uint4*)&As[srow * 40 + scol] = a0;
    {
      uint4 tb = {b2pk(b0.x, b0.y), b2pk(b0.z, b0.w),
                  b2pk(b1.x, b1.y), b2pk(b1.z, b1.w)};
      *(uint4*)&Bs[srow * 40 + scol] = tb;
    }
    __syncthreads();
    if (kc + 32 < 1024) {
      a0 = *(const uint4*)(ap + kc + 32);
      b0 = *(const float4*)(bp + kc + 32);
      b1 = *(const float4*)(bp + kc + 36);
    }
    const bf16x8 af = *(const bf16x8*)&As[(w * 16 + l15) * 40 + quad * 8];
#pragma unroll
    for (int nt = 0; nt < 4; ++nt) {
      const bf16x8 bfr = *(const bf16x8*)&Bs[(nt * 16 + l15) * 40 + quad * 8];
      acc[nt] = __builtin_amdgcn_mfma_f32_16x16x32_bf16(af, bfr, acc[nt], 0, 0, 0);
    }
  }
  float bias_v[4];
#pragma unroll
  for (int nt = 0; nt < 4; ++nt) bias_v[nt] = bias[n0 + nt * 16 + l15];
  __syncthreads();   // staging reads done; reuse smem
  float* Cw = smemf + w * 1088;   // per-wave [16][68]
#pragma unroll
  for (int nt = 0; nt < 4; ++nt)
#pragma unroll
    for (int r = 0; r < 4; ++r)
      Cw[(quad * 4 + r) * 68 + nt * 16 + l15] = acc[nt][r] + bias_v[nt];
  // wave-local: no barrier
#pragma unroll
  for (int p = 0; p < 4; ++p) {
    const int row = p * 4 + (lane >> 4);
    const int c4  = (lane & 15) * 4;
    const float4 v = *(const float4*)&Cw[row * 68 + c4];
    *(float4*)(out + (size_t)(m0 + w * 16 + row) * 512 + n0 + c4) = v;
  }
}

extern "C" void kernel_launch(void* const* d_in, const int* in_sizes, int n_in,
                              void* d_out, int out_size, void* d_ws, size_t ws_size,
                              hipStream_t stream) {
  (void)in_sizes; (void)n_in; (void)out_size; (void)ws_size;
  const float* x     = (const float*)d_in[0];
  const float* w_qkv = (const float*)d_in[1];
  const float* w_out = (const float*)d_in[2];
  const float* b_out = (const float*)d_in[3];
  float* out = (float*)d_out;
  u16* qkvt  = (u16*)d_ws;                          // [0, 16M)
  u16* out12 = (u16*)d_ws + 8ull * 1024 * 1024;     // [16M, 24M)
  k_gemm_qkvt<<<dim3(16, 32), 256, 0, stream>>>(x, w_qkv, qkvt);
  k_attn     <<<dim3(16, 32), 256, 0, stream>>>(qkvt, out12);
  k_band     <<<dim3(8, 16), 256, 0, stream>>>(qkvt, out12);
  k_gemm_out <<<dim3(8, 64), 256, 0, stream>>>(out12, w_out, b_out, out);
}